// Round 1
// 1458.767 us; speedup vs baseline: 1.0863x; 1.0863x over previous
//
#include <hip/hip_runtime.h>
#include <math.h>

#define N_NODES 600000
#define N_EDGES 2400000
#define HD 64
#define F_IN 128
#define LEADS 12
#define NUM_GRAPHS 50000
#define OUT_DIM 32
#define SCAN_BLOCKS 586  // ceil(600000/1024)

// ---------------- CSR build ----------------
__global__ __launch_bounds__(256) void k_zero(int* __restrict__ cnt) {
    int i = blockIdx.x * 256 + threadIdx.x;
    if (i < N_NODES) cnt[i] = 0;
}

// histogram AND per-edge rank (return value of the atomic). The atomic
// round-trip happens here once; k_fill no longer needs an atomic at all.
__global__ __launch_bounds__(256) void k_hist(const int* __restrict__ dst,
                                              int* __restrict__ cnt,
                                              int* __restrict__ rank) {
    int e = blockIdx.x * 256 + threadIdx.x;
    if (e < N_EDGES) rank[e] = atomicAdd(&cnt[dst[e]], 1);
}

__global__ __launch_bounds__(256) void k_scan1(const int* __restrict__ cnt,
                                               int* __restrict__ offs,
                                               int* __restrict__ bsum,
                                               float* __restrict__ dinv) {
    __shared__ int lds[256];
    int t = threadIdx.x;
    int base = blockIdx.x * 1024 + t * 4;
    int v[4];
#pragma unroll
    for (int j = 0; j < 4; ++j) v[j] = (base + j < N_NODES) ? cnt[base + j] : 0;
    // fused dinv: deg + self-loop
#pragma unroll
    for (int j = 0; j < 4; ++j)
        if (base + j < N_NODES) dinv[base + j] = rsqrtf((float)(v[j] + 1));
    int s = v[0] + v[1] + v[2] + v[3];
    lds[t] = s;
    __syncthreads();
    int val = s;
    for (int off = 1; off < 256; off <<= 1) {
        int other = (t >= off) ? lds[t - off] : 0;
        __syncthreads();
        val += other;
        lds[t] = val;
        __syncthreads();
    }
    if (t == 255) bsum[blockIdx.x] = val;
    int run = val - s;
#pragma unroll
    for (int j = 0; j < 4; ++j) {
        if (base + j < N_NODES) offs[base + j] = run;
        run += v[j];
    }
}

__global__ __launch_bounds__(256) void k_scan2(int* __restrict__ bsum) {
    __shared__ int lds[SCAN_BLOCKS];
    for (int i = threadIdx.x; i < SCAN_BLOCKS; i += 256) lds[i] = bsum[i];
    __syncthreads();
    if (threadIdx.x == 0) {
        int run = 0;
        for (int i = 0; i < SCAN_BLOCKS; ++i) {
            int c = lds[i];
            lds[i] = run;
            run += c;
        }
    }
    __syncthreads();
    for (int i = threadIdx.x; i < SCAN_BLOCKS; i += 256) bsum[i] = lds[i];
}

__global__ __launch_bounds__(256) void k_scan3(int* __restrict__ offs,
                                               const int* __restrict__ bsum) {
    int i = blockIdx.x * 256 + threadIdx.x;
    if (i < N_NODES) offs[i] += bsum[i >> 10];
}

// atomic-free fill: position = segment base + precomputed rank.
// offs is 2.4 MB -> random reads are L2 hits; only the eidx scatter
// store (inherent to unsorted edges) remains.
__global__ __launch_bounds__(256) void k_fill(const int* __restrict__ src,
                                              const int* __restrict__ dst,
                                              const int* __restrict__ rank,
                                              const int* __restrict__ offs,
                                              int* __restrict__ eidx) {
    int e = blockIdx.x * 256 + threadIdx.x;
    if (e < N_EDGES) {
        int p = offs[dst[e]] + rank[e];
        eidx[p] = src[e];
    }
}

// ---------------- GEMM: lane=row, scalar W, 16 cols per wave --------------------
// t'[r][c] = dinv[r] * sum_k in[r][k] * W[k][c].  64 rows per block, wave w -> cols [16w,16w+16)
template <int K>
__global__ __launch_bounds__(256) void k_gemm(const float* __restrict__ in,
                                              const float* __restrict__ W,
                                              const float* __restrict__ dinv,
                                              float* __restrict__ tout) {
    __shared__ float lx[64 * (K + 1)];
    const int t = threadIdx.x;
    const int lane = t & 63;
    const int r0 = blockIdx.x * 64;

    // stage 64 rows, coalesced float4, scalar writes into padded LDS (stride K+1)
#pragma unroll
    for (int i = 0; i < K / 16; ++i) {
        int f = (t + i * 256) * 4;
        int r = f / K, k = f % K;
        float4 v = *(const float4*)(in + (size_t)(r0 + r) * K + k);
        float* p = &lx[r * (K + 1) + k];
        p[0] = v.x; p[1] = v.y; p[2] = v.z; p[3] = v.w;
    }
    __syncthreads();

    // wave-uniform column base so W loads become s_load
    const int c0 = __builtin_amdgcn_readfirstlane((t >> 6) * 16);
    const float* Wp = W + c0;

    float acc[16];
#pragma unroll
    for (int cc = 0; cc < 16; ++cc) acc[cc] = 0.0f;

#pragma unroll
    for (int k = 0; k < K; ++k) {
        float xk = lx[lane * (K + 1) + k];  // stride K+1 -> conflict-free
#pragma unroll
        for (int cc = 0; cc < 16; ++cc)
            acc[cc] = fmaf(xk, Wp[k * HD + cc], acc[cc]);  // SGPR operand
    }

    float di = dinv[r0 + lane];
#pragma unroll
    for (int cc = 0; cc < 16; ++cc) acc[cc] *= di;

    __syncthreads();  // reuse lx as transpose buffer (stride 65)
#pragma unroll
    for (int cc = 0; cc < 16; ++cc) lx[lane * 65 + c0 + cc] = acc[cc];
    __syncthreads();

    const int w = t >> 6;
#pragma unroll
    for (int i = 0; i < 16; ++i) {
        int r = i * 4 + w;
        tout[(size_t)(r0 + r) * HD + lane] = lx[r * 65 + lane];
    }
}

// ---------------- gather: 4 nodes/wave, 16 lanes x float4 each --------------------
__global__ __launch_bounds__(256) void k_gather(const float* __restrict__ tp,
                                                const int* __restrict__ eidx,
                                                const int* __restrict__ offs,
                                                const int* __restrict__ cnt,
                                                const float* __restrict__ dinv,
                                                const float* __restrict__ bias,
                                                float* __restrict__ h) {
    const int wave = (blockIdx.x * 256 + threadIdx.x) >> 6;
    const int lane = threadIdx.x & 63;
    const int grp = lane >> 4, sl = lane & 15;
    const int node = wave * 4 + grp;

    const float4* tp4 = (const float4*)tp;
    float4 a0 = tp4[(size_t)node * 16 + sl];  // self-loop
    float4 a1 = {0.0f, 0.0f, 0.0f, 0.0f};

    const int start = offs[node];
    const int c = cnt[node];

    // wave-uniform trip count = max degree in wave
    int cm = c;
#pragma unroll
    for (int off = 32; off >= 1; off >>= 1) cm = max(cm, __shfl_xor(cm, off));

    int j = 0;
    for (; j + 1 < cm; j += 2) {
        if (j < c) {
            int s0 = eidx[start + j];
            float4 v = tp4[(size_t)s0 * 16 + sl];
            a0.x += v.x; a0.y += v.y; a0.z += v.z; a0.w += v.w;
        }
        if (j + 1 < c) {
            int s1 = eidx[start + j + 1];
            float4 v = tp4[(size_t)s1 * 16 + sl];
            a1.x += v.x; a1.y += v.y; a1.z += v.z; a1.w += v.w;
        }
    }
    if (j < c) {
        int s0 = eidx[start + j];
        float4 v = tp4[(size_t)s0 * 16 + sl];
        a0.x += v.x; a0.y += v.y; a0.z += v.z; a0.w += v.w;
    }

    const float di = dinv[node];
    const float4 b4 = *(const float4*)(bias + sl * 4);
    float4 r;
    r.x = fmaxf(fmaf(di, a0.x + a1.x, b4.x), 0.0f);
    r.y = fmaxf(fmaf(di, a0.y + a1.y, b4.y), 0.0f);
    r.z = fmaxf(fmaf(di, a0.z + a1.z, b4.z), 0.0f);
    r.w = fmaxf(fmaf(di, a0.w + a1.w, b4.w), 0.0f);
    ((float4*)h)[(size_t)node * 16 + sl] = r;
}

// ---------------- lead attention + pool + linear ----------------
__global__ __launch_bounds__(256) void k_attn(const float* __restrict__ h3,
                                              const float* __restrict__ Wa,
                                              const float* __restrict__ vvec,
                                              const float* __restrict__ Wl,
                                              const float* __restrict__ bl,
                                              float* __restrict__ out,
                                              float* __restrict__ lw) {
    __shared__ float lds_Wl[128 * 32];
    __shared__ float lds_h[4][LEADS * 64];
    __shared__ float lds_p[4][128];
    const int t = threadIdx.x;
    const int lane = t & 63;
    const int wid = t >> 6;

#pragma unroll
    for (int i = 0; i < 16; ++i) lds_Wl[t + i * 256] = Wl[t + i * 256];

    float wa[64];
#pragma unroll
    for (int k = 0; k < 64; ++k) wa[k] = Wa[k * 64 + lane];
    float vl = vvec[lane];
    __syncthreads();

    const int g = blockIdx.x * 4 + wid;

    float hv[LEADS];
#pragma unroll
    for (int r = 0; r < LEADS; ++r) {
        hv[r] = h3[(size_t)(g * LEADS + r) * 64 + lane];
        lds_h[wid][r * 64 + lane] = hv[r];
    }

    float s_[LEADS];
#pragma unroll
    for (int r = 0; r < LEADS; ++r) {
        float acc = 0.0f;
        const float4* h4 = (const float4*)&lds_h[wid][r * 64];
#pragma unroll
        for (int k4 = 0; k4 < 16; ++k4) {
            float4 hb = h4[k4];  // broadcast read
            acc = fmaf(hb.x, wa[4 * k4 + 0], acc);
            acc = fmaf(hb.y, wa[4 * k4 + 1], acc);
            acc = fmaf(hb.z, wa[4 * k4 + 2], acc);
            acc = fmaf(hb.w, wa[4 * k4 + 3], acc);
        }
        float sc = tanhf(acc) * vl;
#pragma unroll
        for (int off = 32; off >= 1; off >>= 1) sc += __shfl_xor(sc, off);
        s_[r] = sc;
    }

    float m = s_[0];
#pragma unroll
    for (int r = 1; r < LEADS; ++r) m = fmaxf(m, s_[r]);
    float wgt[LEADS];
    float sum = 0.0f;
#pragma unroll
    for (int r = 0; r < LEADS; ++r) {
        wgt[r] = expf(s_[r] - m);
        sum += wgt[r];
    }
    float inv = 1.0f / sum;

    float tmp = wgt[0] * inv;
#pragma unroll
    for (int r = 1; r < LEADS; ++r) tmp = (lane == r) ? wgt[r] * inv : tmp;
    if (lane < LEADS) lw[g * LEADS + lane] = tmp;

    float gmax = -1e30f, gsum = 0.0f;
#pragma unroll
    for (int r = 0; r < LEADS; ++r) {
        float wh = hv[r] * (wgt[r] * inv);
        gmax = fmaxf(gmax, wh);
        gsum += wh;
    }
    lds_p[wid][lane] = gmax;
    lds_p[wid][64 + lane] = gsum * (1.0f / 12.0f);

    int o = lane & 31, half = lane >> 5;
    float acc2 = 0.0f;
#pragma unroll
    for (int k = 0; k < 64; ++k) {
        int kk = half * 64 + k;
        acc2 = fmaf(lds_p[wid][kk], lds_Wl[kk * 32 + o], acc2);
    }
    acc2 += __shfl_xor(acc2, 32);
    if (lane < 32) out[g * 32 + lane] = fmaxf(acc2 + bl[lane], 0.0f);
}

// ---------------- launch ----------------
extern "C" void kernel_launch(void* const* d_in, const int* in_sizes, int n_in,
                              void* d_out, int out_size, void* d_ws, size_t ws_size,
                              hipStream_t stream) {
    const float* x  = (const float*)d_in[0];
    const int* ei   = (const int*)d_in[1];
    const int* src  = ei;
    const int* dst  = ei + N_EDGES;
    const float* W1 = (const float*)d_in[3];
    const float* b1 = (const float*)d_in[4];
    const float* W2 = (const float*)d_in[5];
    const float* b2 = (const float*)d_in[6];
    const float* W3 = (const float*)d_in[7];
    const float* b3 = (const float*)d_in[8];
    const float* Wa = (const float*)d_in[9];
    const float* vv = (const float*)d_in[10];
    const float* Wl = (const float*)d_in[11];
    const float* bl = (const float*)d_in[12];

    float* out = (float*)d_out;
    float* lw  = out + (size_t)NUM_GRAPHS * 32;

    float* dinv = (float*)d_ws;                       // N f32
    int* cnt    = (int*)(dinv + N_NODES);             // N
    int* offs   = cnt + N_NODES;                      // N
    int* bsum   = offs + N_NODES;                     // 1024
    int* eidx   = bsum + 1024;                        // E
    float* T    = (float*)(eidx + N_EDGES);           // N*64
    float* Hb   = T + (size_t)N_NODES * HD;           // N*64
    // rank aliases T: T is first written by k_gemm, strictly after k_fill
    // consumed rank (in-order stream).
    int* rank   = (int*)T;                            // E (aliased)

    const int gN = (N_NODES + 255) / 256;
    const int gE = (N_EDGES + 255) / 256;

    k_zero<<<gN, 256, 0, stream>>>(cnt);
    k_hist<<<gE, 256, 0, stream>>>(dst, cnt, rank);
    k_scan1<<<SCAN_BLOCKS, 256, 0, stream>>>(cnt, offs, bsum, dinv);
    k_scan2<<<1, 256, 0, stream>>>(bsum);
    k_scan3<<<gN, 256, 0, stream>>>(offs, bsum);
    k_fill<<<gE, 256, 0, stream>>>(src, dst, rank, offs, eidx);

    // layer 1
    k_gemm<128><<<N_NODES / 64, 256, 0, stream>>>(x, W1, dinv, T);
    k_gather<<<N_NODES / 16, 256, 0, stream>>>(T, eidx, offs, cnt, dinv, b1, Hb);
    // layer 2
    k_gemm<64><<<N_NODES / 64, 256, 0, stream>>>(Hb, W2, dinv, T);
    k_gather<<<N_NODES / 16, 256, 0, stream>>>(T, eidx, offs, cnt, dinv, b2, Hb);
    // layer 3
    k_gemm<64><<<N_NODES / 64, 256, 0, stream>>>(Hb, W3, dinv, T);
    k_gather<<<N_NODES / 16, 256, 0, stream>>>(T, eidx, offs, cnt, dinv, b3, Hb);
    // attention + pool + linear
    k_attn<<<NUM_GRAPHS / 4, 256, 0, stream>>>(Hb, Wa, vv, Wl, bl, out, lw);
}

// Round 3
// 1438.297 us; speedup vs baseline: 1.1017x; 1.0142x over previous
//
#include <hip/hip_runtime.h>
#include <math.h>

#define N_NODES 600000
#define N_EDGES 2400000
#define HD 64
#define F_IN 128
#define LEADS 12
#define NUM_GRAPHS 50000
#define OUT_DIM 32
#define SCAN_BLOCKS 586  // ceil(600000/1024)

// ---------------- CSR build ----------------
__global__ __launch_bounds__(256) void k_zero(int* __restrict__ cnt) {
    int i = blockIdx.x * 256 + threadIdx.x;
    if (i < N_NODES) cnt[i] = 0;
}

// histogram AND per-edge rank (return value of the atomic). The atomic
// round-trip happens here once; k_fill no longer needs an atomic at all.
__global__ __launch_bounds__(256) void k_hist(const int* __restrict__ dst,
                                              int* __restrict__ cnt,
                                              int* __restrict__ rank) {
    int e = blockIdx.x * 256 + threadIdx.x;
    if (e < N_EDGES) rank[e] = atomicAdd(&cnt[dst[e]], 1);
}

__global__ __launch_bounds__(256) void k_scan1(const int* __restrict__ cnt,
                                               int* __restrict__ offs,
                                               int* __restrict__ bsum,
                                               float* __restrict__ dinv) {
    __shared__ int lds[256];
    int t = threadIdx.x;
    int base = blockIdx.x * 1024 + t * 4;
    int v[4];
#pragma unroll
    for (int j = 0; j < 4; ++j) v[j] = (base + j < N_NODES) ? cnt[base + j] : 0;
    // fused dinv: deg + self-loop
#pragma unroll
    for (int j = 0; j < 4; ++j)
        if (base + j < N_NODES) dinv[base + j] = rsqrtf((float)(v[j] + 1));
    int s = v[0] + v[1] + v[2] + v[3];
    lds[t] = s;
    __syncthreads();
    int val = s;
    for (int off = 1; off < 256; off <<= 1) {
        int other = (t >= off) ? lds[t - off] : 0;
        __syncthreads();
        val += other;
        lds[t] = val;
        __syncthreads();
    }
    if (t == 255) bsum[blockIdx.x] = val;
    int run = val - s;
#pragma unroll
    for (int j = 0; j < 4; ++j) {
        if (base + j < N_NODES) offs[base + j] = run;
        run += v[j];
    }
}

__global__ __launch_bounds__(256) void k_scan2(int* __restrict__ bsum) {
    __shared__ int lds[SCAN_BLOCKS];
    for (int i = threadIdx.x; i < SCAN_BLOCKS; i += 256) lds[i] = bsum[i];
    __syncthreads();
    if (threadIdx.x == 0) {
        int run = 0;
        for (int i = 0; i < SCAN_BLOCKS; ++i) {
            int c = lds[i];
            lds[i] = run;
            run += c;
        }
    }
    __syncthreads();
    for (int i = threadIdx.x; i < SCAN_BLOCKS; i += 256) bsum[i] = lds[i];
}

__global__ __launch_bounds__(256) void k_scan3(int* __restrict__ offs,
                                               const int* __restrict__ bsum) {
    int i = blockIdx.x * 256 + threadIdx.x;
    if (i < N_NODES) offs[i] += bsum[i >> 10];
}

// atomic-free fill: position = segment base + precomputed rank.
__global__ __launch_bounds__(256) void k_fill(const int* __restrict__ src,
                                              const int* __restrict__ dst,
                                              const int* __restrict__ rank,
                                              const int* __restrict__ offs,
                                              int* __restrict__ eidx) {
    int e = blockIdx.x * 256 + threadIdx.x;
    if (e < N_EDGES) {
        int p = offs[dst[e]] + rank[e];
        eidx[p] = src[e];
    }
}

// ---------------- GEMM: lane=row, scalar W, 16 cols per wave --------------------
// t'[r][c] = dinv[r] * sum_k in[r][k] * W[k][c].  64 rows per block, wave w -> cols [16w,16w+16)
template <int K>
__global__ __launch_bounds__(256) void k_gemm(const float* __restrict__ in,
                                              const float* __restrict__ W,
                                              const float* __restrict__ dinv,
                                              float* __restrict__ tout) {
    __shared__ float lx[64 * (K + 1)];
    const int t = threadIdx.x;
    const int lane = t & 63;
    const int r0 = blockIdx.x * 64;

    // stage 64 rows, coalesced float4, scalar writes into padded LDS (stride K+1)
#pragma unroll
    for (int i = 0; i < K / 16; ++i) {
        int f = (t + i * 256) * 4;
        int r = f / K, k = f % K;
        float4 v = *(const float4*)(in + (size_t)(r0 + r) * K + k);
        float* p = &lx[r * (K + 1) + k];
        p[0] = v.x; p[1] = v.y; p[2] = v.z; p[3] = v.w;
    }
    __syncthreads();

    // wave-uniform column base so W loads become s_load
    const int c0 = __builtin_amdgcn_readfirstlane((t >> 6) * 16);
    const float* Wp = W + c0;

    float acc[16];
#pragma unroll
    for (int cc = 0; cc < 16; ++cc) acc[cc] = 0.0f;

#pragma unroll
    for (int k = 0; k < K; ++k) {
        float xk = lx[lane * (K + 1) + k];  // stride K+1 -> conflict-free
#pragma unroll
        for (int cc = 0; cc < 16; ++cc)
            acc[cc] = fmaf(xk, Wp[k * HD + cc], acc[cc]);  // SGPR operand
    }

    float di = dinv[r0 + lane];
#pragma unroll
    for (int cc = 0; cc < 16; ++cc) acc[cc] *= di;

    __syncthreads();  // reuse lx as transpose buffer (stride 65)
#pragma unroll
    for (int cc = 0; cc < 16; ++cc) lx[lane * 65 + c0 + cc] = acc[cc];
    __syncthreads();

    const int w = t >> 6;
#pragma unroll
    for (int i = 0; i < 16; ++i) {
        int r = i * 4 + w;
        tout[(size_t)(r0 + r) * HD + lane] = lx[r * 65 + lane];
    }
}

// ---------------- fused gather(layer i) + gemm(layer i+1) ----------------
// Per block: 64 nodes. Gather phase writes relu(di*agg + b) straight into the
// padded LDS tile (stride 65); gemm phase consumes it without the global
// Hb round-trip (saves 307 MB of traffic per junction).
__global__ __launch_bounds__(256) void k_fused(const float* __restrict__ tp,
                                               const int* __restrict__ eidx,
                                               const int* __restrict__ offs,
                                               const int* __restrict__ cnt,
                                               const float* __restrict__ dinv,
                                               const float* __restrict__ bias,
                                               const float* __restrict__ W,
                                               float* __restrict__ tout) {
    __shared__ float lhx[64 * 65];
    const int t = threadIdx.x;
    const int lane = t & 63;
    const int w = t >> 6;
    const int r0 = blockIdx.x * 64;
    const int grp = lane >> 4, sl = lane & 15;

    const float4* tp4 = (const float4*)tp;
    const float4 b4 = *(const float4*)(bias + sl * 4);

    // ---- gather phase: 4 passes x (4 waves x 4 nodes) = 64 nodes ----
#pragma unroll
    for (int p = 0; p < 4; ++p) {
        const int nl = p * 16 + w * 4 + grp;  // node_local in [0,64)
        const int node = r0 + nl;

        float4 a0 = tp4[(size_t)node * 16 + sl];  // self-loop
        float4 a1 = {0.0f, 0.0f, 0.0f, 0.0f};

        const int start = offs[node];
        const int c = cnt[node];

        int cm = c;  // wave-uniform trip count
#pragma unroll
        for (int off = 32; off >= 1; off >>= 1) cm = max(cm, __shfl_xor(cm, off));

        int j = 0;
        for (; j + 1 < cm; j += 2) {
            if (j < c) {
                int s0 = eidx[start + j];
                float4 v = tp4[(size_t)s0 * 16 + sl];
                a0.x += v.x; a0.y += v.y; a0.z += v.z; a0.w += v.w;
            }
            if (j + 1 < c) {
                int s1 = eidx[start + j + 1];
                float4 v = tp4[(size_t)s1 * 16 + sl];
                a1.x += v.x; a1.y += v.y; a1.z += v.z; a1.w += v.w;
            }
        }
        if (j < c) {
            int s0 = eidx[start + j];
            float4 v = tp4[(size_t)s0 * 16 + sl];
            a0.x += v.x; a0.y += v.y; a0.z += v.z; a0.w += v.w;
        }

        const float di = dinv[node];
        float* pl = &lhx[nl * 65 + sl * 4];
        pl[0] = fmaxf(fmaf(di, a0.x + a1.x, b4.x), 0.0f);
        pl[1] = fmaxf(fmaf(di, a0.y + a1.y, b4.y), 0.0f);
        pl[2] = fmaxf(fmaf(di, a0.z + a1.z, b4.z), 0.0f);
        pl[3] = fmaxf(fmaf(di, a0.w + a1.w, b4.w), 0.0f);
    }
    __syncthreads();

    // ---- gemm phase (K=64), input already in LDS ----
    const int c0 = __builtin_amdgcn_readfirstlane(w * 16);
    const float* Wp = W + c0;

    float acc[16];
#pragma unroll
    for (int cc = 0; cc < 16; ++cc) acc[cc] = 0.0f;

#pragma unroll
    for (int k = 0; k < HD; ++k) {
        float xk = lhx[lane * 65 + k];
#pragma unroll
        for (int cc = 0; cc < 16; ++cc)
            acc[cc] = fmaf(xk, Wp[k * HD + cc], acc[cc]);
    }

    float di2 = dinv[r0 + lane];  // source-side scale for NEXT aggregation
#pragma unroll
    for (int cc = 0; cc < 16; ++cc) acc[cc] *= di2;

    __syncthreads();  // reuse lhx as transpose buffer
#pragma unroll
    for (int cc = 0; cc < 16; ++cc) lhx[lane * 65 + c0 + cc] = acc[cc];
    __syncthreads();

#pragma unroll
    for (int i = 0; i < 16; ++i) {
        int r = i * 4 + w;
        tout[(size_t)(r0 + r) * HD + lane] = lhx[r * 65 + lane];
    }
}

// ---------------- gather: 4 nodes/wave, 16 lanes x float4 each --------------------
__global__ __launch_bounds__(256) void k_gather(const float* __restrict__ tp,
                                                const int* __restrict__ eidx,
                                                const int* __restrict__ offs,
                                                const int* __restrict__ cnt,
                                                const float* __restrict__ dinv,
                                                const float* __restrict__ bias,
                                                float* __restrict__ h) {
    const int wave = (blockIdx.x * 256 + threadIdx.x) >> 6;
    const int lane = threadIdx.x & 63;
    const int grp = lane >> 4, sl = lane & 15;
    const int node = wave * 4 + grp;

    const float4* tp4 = (const float4*)tp;
    float4 a0 = tp4[(size_t)node * 16 + sl];  // self-loop
    float4 a1 = {0.0f, 0.0f, 0.0f, 0.0f};

    const int start = offs[node];
    const int c = cnt[node];

    // wave-uniform trip count = max degree in wave
    int cm = c;
#pragma unroll
    for (int off = 32; off >= 1; off >>= 1) cm = max(cm, __shfl_xor(cm, off));

    int j = 0;
    for (; j + 1 < cm; j += 2) {
        if (j < c) {
            int s0 = eidx[start + j];
            float4 v = tp4[(size_t)s0 * 16 + sl];
            a0.x += v.x; a0.y += v.y; a0.z += v.z; a0.w += v.w;
        }
        if (j + 1 < c) {
            int s1 = eidx[start + j + 1];
            float4 v = tp4[(size_t)s1 * 16 + sl];
            a1.x += v.x; a1.y += v.y; a1.z += v.z; a1.w += v.w;
        }
    }
    if (j < c) {
        int s0 = eidx[start + j];
        float4 v = tp4[(size_t)s0 * 16 + sl];
        a0.x += v.x; a0.y += v.y; a0.z += v.z; a0.w += v.w;
    }

    const float di = dinv[node];
    const float4 b4 = *(const float4*)(bias + sl * 4);
    float4 r;
    r.x = fmaxf(fmaf(di, a0.x + a1.x, b4.x), 0.0f);
    r.y = fmaxf(fmaf(di, a0.y + a1.y, b4.y), 0.0f);
    r.z = fmaxf(fmaf(di, a0.z + a1.z, b4.z), 0.0f);
    r.w = fmaxf(fmaf(di, a0.w + a1.w, b4.w), 0.0f);
    ((float4*)h)[(size_t)node * 16 + sl] = r;
}

// ---------------- lead attention + pool + linear ----------------
__global__ __launch_bounds__(256) void k_attn(const float* __restrict__ h3,
                                              const float* __restrict__ Wa,
                                              const float* __restrict__ vvec,
                                              const float* __restrict__ Wl,
                                              const float* __restrict__ bl,
                                              float* __restrict__ out,
                                              float* __restrict__ lw) {
    __shared__ float lds_Wl[128 * 32];
    __shared__ float lds_h[4][LEADS * 64];
    __shared__ float lds_p[4][128];
    const int t = threadIdx.x;
    const int lane = t & 63;
    const int wid = t >> 6;

#pragma unroll
    for (int i = 0; i < 16; ++i) lds_Wl[t + i * 256] = Wl[t + i * 256];

    float wa[64];
#pragma unroll
    for (int k = 0; k < 64; ++k) wa[k] = Wa[k * 64 + lane];
    float vl = vvec[lane];
    __syncthreads();

    const int g = blockIdx.x * 4 + wid;

    float hv[LEADS];
#pragma unroll
    for (int r = 0; r < LEADS; ++r) {
        hv[r] = h3[(size_t)(g * LEADS + r) * 64 + lane];
        lds_h[wid][r * 64 + lane] = hv[r];
    }

    float s_[LEADS];
#pragma unroll
    for (int r = 0; r < LEADS; ++r) {
        float acc = 0.0f;
        const float4* h4 = (const float4*)&lds_h[wid][r * 64];
#pragma unroll
        for (int k4 = 0; k4 < 16; ++k4) {
            float4 hb = h4[k4];  // broadcast read
            acc = fmaf(hb.x, wa[4 * k4 + 0], acc);
            acc = fmaf(hb.y, wa[4 * k4 + 1], acc);
            acc = fmaf(hb.z, wa[4 * k4 + 2], acc);
            acc = fmaf(hb.w, wa[4 * k4 + 3], acc);
        }
        float sc = tanhf(acc) * vl;
#pragma unroll
        for (int off = 32; off >= 1; off >>= 1) sc += __shfl_xor(sc, off);
        s_[r] = sc;
    }

    float m = s_[0];
#pragma unroll
    for (int r = 1; r < LEADS; ++r) m = fmaxf(m, s_[r]);
    float wgt[LEADS];
    float sum = 0.0f;
#pragma unroll
    for (int r = 0; r < LEADS; ++r) {
        wgt[r] = expf(s_[r] - m);
        sum += wgt[r];
    }
    float inv = 1.0f / sum;

    float tmp = wgt[0] * inv;
#pragma unroll
    for (int r = 1; r < LEADS; ++r) tmp = (lane == r) ? wgt[r] * inv : tmp;
    if (lane < LEADS) lw[g * LEADS + lane] = tmp;

    float gmax = -1e30f, gsum = 0.0f;
#pragma unroll
    for (int r = 0; r < LEADS; ++r) {
        float wh = hv[r] * (wgt[r] * inv);
        gmax = fmaxf(gmax, wh);
        gsum += wh;
    }
    lds_p[wid][lane] = gmax;
    lds_p[wid][64 + lane] = gsum * (1.0f / 12.0f);

    int o = lane & 31, half = lane >> 5;
    float acc2 = 0.0f;
#pragma unroll
    for (int k = 0; k < 64; ++k) {
        int kk = half * 64 + k;
        acc2 = fmaf(lds_p[wid][kk], lds_Wl[kk * 32 + o], acc2);
    }
    acc2 += __shfl_xor(acc2, 32);
    if (lane < 32) out[g * 32 + lane] = fmaxf(acc2 + bl[lane], 0.0f);
}

// ---------------- launch ----------------
extern "C" void kernel_launch(void* const* d_in, const int* in_sizes, int n_in,
                              void* d_out, int out_size, void* d_ws, size_t ws_size,
                              hipStream_t stream) {
    const float* x  = (const float*)d_in[0];
    const int* ei   = (const int*)d_in[1];
    const int* src  = ei;
    const int* dst  = ei + N_EDGES;
    const float* W1 = (const float*)d_in[3];
    const float* b1 = (const float*)d_in[4];
    const float* W2 = (const float*)d_in[5];
    const float* b2 = (const float*)d_in[6];
    const float* W3 = (const float*)d_in[7];
    const float* b3 = (const float*)d_in[8];
    const float* Wa = (const float*)d_in[9];
    const float* vv = (const float*)d_in[10];
    const float* Wl = (const float*)d_in[11];
    const float* bl = (const float*)d_in[12];

    float* out = (float*)d_out;
    float* lw  = out + (size_t)NUM_GRAPHS * 32;

    float* dinv = (float*)d_ws;                       // N f32
    int* cnt    = (int*)(dinv + N_NODES);             // N
    int* offs   = cnt + N_NODES;                      // N
    int* bsum   = offs + N_NODES;                     // 1024
    int* eidx   = bsum + 1024;                        // E
    float* T    = (float*)(eidx + N_EDGES);           // N*64
    float* Hb   = T + (size_t)N_NODES * HD;           // N*64
    // rank aliases T: T is first written by k_gemm, strictly after k_fill
    // consumed rank (in-order stream).
    int* rank   = (int*)T;                            // E (aliased)

    const int gN = (N_NODES + 255) / 256;
    const int gE = (N_EDGES + 255) / 256;

    k_zero<<<gN, 256, 0, stream>>>(cnt);
    k_hist<<<gE, 256, 0, stream>>>(dst, cnt, rank);
    k_scan1<<<SCAN_BLOCKS, 256, 0, stream>>>(cnt, offs, bsum, dinv);
    k_scan2<<<1, 256, 0, stream>>>(bsum);
    k_scan3<<<gN, 256, 0, stream>>>(offs, bsum);
    k_fill<<<gE, 256, 0, stream>>>(src, dst, rank, offs, eidx);

    // layer 1 transform: T1 = dinv * (x @ W1)
    k_gemm<128><<<N_NODES / 64, 256, 0, stream>>>(x, W1, dinv, T);
    // fused: h1 = relu(agg(T1)+b1) in LDS; T2 = dinv * (h1 @ W2)
    k_fused<<<N_NODES / 64, 256, 0, stream>>>(T, eidx, offs, cnt, dinv, b1, W2, Hb);
    // fused: h2 = relu(agg(T2)+b2) in LDS; T3 = dinv * (h2 @ W3)
    k_fused<<<N_NODES / 64, 256, 0, stream>>>(Hb, eidx, offs, cnt, dinv, b2, W3, T);
    // layer 3 aggregation: h3 = relu(agg(T3)+b3)
    k_gather<<<N_NODES / 16, 256, 0, stream>>>(T, eidx, offs, cnt, dinv, b3, Hb);
    // attention + pool + linear
    k_attn<<<NUM_GRAPHS / 4, 256, 0, stream>>>(Hb, Wa, vv, Wl, bl, out, lw);
}

// Round 4
// 1285.415 us; speedup vs baseline: 1.2328x; 1.1189x over previous
//
#include <hip/hip_runtime.h>
#include <math.h>

#define N_NODES 600000
#define N_EDGES 2400000
#define HD 64
#define F_IN 128
#define LEADS 12
#define NUM_GRAPHS 50000
#define OUT_DIM 32
#define SCAN_BLOCKS 586  // ceil(600000/1024)

// ---------------- CSR build ----------------
__global__ __launch_bounds__(256) void k_zero(int* __restrict__ cnt) {
    int i = blockIdx.x * 256 + threadIdx.x;
    if (i < N_NODES) cnt[i] = 0;
}

// histogram AND per-edge rank (return value of the atomic). The atomic
// round-trip happens here once; k_fill no longer needs an atomic at all.
__global__ __launch_bounds__(256) void k_hist(const int* __restrict__ dst,
                                              int* __restrict__ cnt,
                                              int* __restrict__ rank) {
    int e = blockIdx.x * 256 + threadIdx.x;
    if (e < N_EDGES) rank[e] = atomicAdd(&cnt[dst[e]], 1);
}

__global__ __launch_bounds__(256) void k_scan1(const int* __restrict__ cnt,
                                               int* __restrict__ offs,
                                               int* __restrict__ bsum,
                                               float* __restrict__ dinv) {
    __shared__ int lds[256];
    int t = threadIdx.x;
    int base = blockIdx.x * 1024 + t * 4;
    int v[4];
#pragma unroll
    for (int j = 0; j < 4; ++j) v[j] = (base + j < N_NODES) ? cnt[base + j] : 0;
    // fused dinv: deg + self-loop
#pragma unroll
    for (int j = 0; j < 4; ++j)
        if (base + j < N_NODES) dinv[base + j] = rsqrtf((float)(v[j] + 1));
    int s = v[0] + v[1] + v[2] + v[3];
    lds[t] = s;
    __syncthreads();
    int val = s;
    for (int off = 1; off < 256; off <<= 1) {
        int other = (t >= off) ? lds[t - off] : 0;
        __syncthreads();
        val += other;
        lds[t] = val;
        __syncthreads();
    }
    if (t == 255) bsum[blockIdx.x] = val;
    int run = val - s;
#pragma unroll
    for (int j = 0; j < 4; ++j) {
        if (base + j < N_NODES) offs[base + j] = run;
        run += v[j];
    }
}

__global__ __launch_bounds__(256) void k_scan2(int* __restrict__ bsum) {
    __shared__ int lds[SCAN_BLOCKS];
    for (int i = threadIdx.x; i < SCAN_BLOCKS; i += 256) lds[i] = bsum[i];
    __syncthreads();
    if (threadIdx.x == 0) {
        int run = 0;
        for (int i = 0; i < SCAN_BLOCKS; ++i) {
            int c = lds[i];
            lds[i] = run;
            run += c;
        }
    }
    __syncthreads();
    for (int i = threadIdx.x; i < SCAN_BLOCKS; i += 256) bsum[i] = lds[i];
}

__global__ __launch_bounds__(256) void k_scan3(int* __restrict__ offs,
                                               const int* __restrict__ bsum) {
    int i = blockIdx.x * 256 + threadIdx.x;
    if (i < N_NODES) offs[i] += bsum[i >> 10];
}

// atomic-free fill: position = segment base + precomputed rank.
__global__ __launch_bounds__(256) void k_fill(const int* __restrict__ src,
                                              const int* __restrict__ dst,
                                              const int* __restrict__ rank,
                                              const int* __restrict__ offs,
                                              int* __restrict__ eidx) {
    int e = blockIdx.x * 256 + threadIdx.x;
    if (e < N_EDGES) {
        int p = offs[dst[e]] + rank[e];
        eidx[p] = src[e];
    }
}

// ---------------- latency-optimized per-node edge gather ----------------
// 16-lane group accumulates 64 feature floats (float4/lane) over the node's
// edge list. Edge indices are prefetched coalesced (lane sl loads
// eidx[start+sl]) and distributed via shfl; 4 row-loads kept in flight,
// branch-free: masked slots load the node's OWN row (L1-hot) and are
// nulled via fmaf(mask, ...). cm must be the wave-uniform max degree.
__device__ __forceinline__ float4 gcn_gather(const float4* __restrict__ tp4,
                                             const int* __restrict__ eidx,
                                             int node, int start, int c, int cm,
                                             int sl, int grpBase) {
    float4 a0 = tp4[(size_t)node * 16 + sl];  // self-loop
    float4 a1 = {0.0f, 0.0f, 0.0f, 0.0f};
    float4 a2 = {0.0f, 0.0f, 0.0f, 0.0f};
    float4 a3 = {0.0f, 0.0f, 0.0f, 0.0f};

    for (int base = 0; base < cm; base += 16) {
        // batch of up to 16 edge indices, one coalesced load per group
        int idxreg = (base + sl < c) ? eidx[start + base + sl] : node;
        int take = cm - base;
        if (take > 16) take = 16;
        for (int j = 0; j < take; j += 4) {
            int i0 = __shfl(idxreg, grpBase + j + 0);
            int i1 = __shfl(idxreg, grpBase + j + 1);
            int i2 = __shfl(idxreg, grpBase + j + 2);
            int i3 = __shfl(idxreg, grpBase + j + 3);
            float m0 = (base + j + 0 < c) ? 1.0f : 0.0f;
            float m1 = (base + j + 1 < c) ? 1.0f : 0.0f;
            float m2 = (base + j + 2 < c) ? 1.0f : 0.0f;
            float m3 = (base + j + 3 < c) ? 1.0f : 0.0f;
            // 4 independent loads in flight (i1..i3 fall back to `node`
            // when masked -> L1 hit, no extra HBM traffic)
            float4 v0 = tp4[(size_t)i0 * 16 + sl];
            float4 v1 = tp4[(size_t)i1 * 16 + sl];
            float4 v2 = tp4[(size_t)i2 * 16 + sl];
            float4 v3 = tp4[(size_t)i3 * 16 + sl];
            a0.x = fmaf(m0, v0.x, a0.x); a0.y = fmaf(m0, v0.y, a0.y);
            a0.z = fmaf(m0, v0.z, a0.z); a0.w = fmaf(m0, v0.w, a0.w);
            a1.x = fmaf(m1, v1.x, a1.x); a1.y = fmaf(m1, v1.y, a1.y);
            a1.z = fmaf(m1, v1.z, a1.z); a1.w = fmaf(m1, v1.w, a1.w);
            a2.x = fmaf(m2, v2.x, a2.x); a2.y = fmaf(m2, v2.y, a2.y);
            a2.z = fmaf(m2, v2.z, a2.z); a2.w = fmaf(m2, v2.w, a2.w);
            a3.x = fmaf(m3, v3.x, a3.x); a3.y = fmaf(m3, v3.y, a3.y);
            a3.z = fmaf(m3, v3.z, a3.z); a3.w = fmaf(m3, v3.w, a3.w);
        }
    }
    a0.x += a1.x + a2.x + a3.x;
    a0.y += a1.y + a2.y + a3.y;
    a0.z += a1.z + a2.z + a3.z;
    a0.w += a1.w + a2.w + a3.w;
    return a0;
}

// ---------------- GEMM: lane=row, scalar W, 16 cols per wave --------------------
// t'[r][c] = dinv[r] * sum_k in[r][k] * W[k][c].  64 rows per block, wave w -> cols [16w,16w+16)
template <int K>
__global__ __launch_bounds__(256) void k_gemm(const float* __restrict__ in,
                                              const float* __restrict__ W,
                                              const float* __restrict__ dinv,
                                              float* __restrict__ tout) {
    __shared__ float lx[64 * (K + 1)];
    const int t = threadIdx.x;
    const int lane = t & 63;
    const int r0 = blockIdx.x * 64;

    // stage 64 rows, coalesced float4, scalar writes into padded LDS (stride K+1)
#pragma unroll
    for (int i = 0; i < K / 16; ++i) {
        int f = (t + i * 256) * 4;
        int r = f / K, k = f % K;
        float4 v = *(const float4*)(in + (size_t)(r0 + r) * K + k);
        float* p = &lx[r * (K + 1) + k];
        p[0] = v.x; p[1] = v.y; p[2] = v.z; p[3] = v.w;
    }
    __syncthreads();

    // wave-uniform column base so W loads become s_load
    const int c0 = __builtin_amdgcn_readfirstlane((t >> 6) * 16);
    const float* Wp = W + c0;

    float acc[16];
#pragma unroll
    for (int cc = 0; cc < 16; ++cc) acc[cc] = 0.0f;

#pragma unroll
    for (int k = 0; k < K; ++k) {
        float xk = lx[lane * (K + 1) + k];  // stride K+1 -> conflict-free
#pragma unroll
        for (int cc = 0; cc < 16; ++cc)
            acc[cc] = fmaf(xk, Wp[k * HD + cc], acc[cc]);  // SGPR operand
    }

    float di = dinv[r0 + lane];
#pragma unroll
    for (int cc = 0; cc < 16; ++cc) acc[cc] *= di;

    __syncthreads();  // reuse lx as transpose buffer (stride 65)
#pragma unroll
    for (int cc = 0; cc < 16; ++cc) lx[lane * 65 + c0 + cc] = acc[cc];
    __syncthreads();

    const int w = t >> 6;
#pragma unroll
    for (int i = 0; i < 16; ++i) {
        int r = i * 4 + w;
        tout[(size_t)(r0 + r) * HD + lane] = lx[r * 65 + lane];
    }
}

// ---------------- fused gather(layer i) + gemm(layer i+1) ----------------
// Per block: 64 nodes. Gather phase writes relu(di*agg + b) straight into the
// padded LDS tile (stride 65); gemm phase consumes it without the global
// Hb round-trip.
__global__ __launch_bounds__(256) void k_fused(const float* __restrict__ tp,
                                               const int* __restrict__ eidx,
                                               const int* __restrict__ offs,
                                               const int* __restrict__ cnt,
                                               const float* __restrict__ dinv,
                                               const float* __restrict__ bias,
                                               const float* __restrict__ W,
                                               float* __restrict__ tout) {
    __shared__ float lhx[64 * 65];
    const int t = threadIdx.x;
    const int lane = t & 63;
    const int w = t >> 6;
    const int r0 = blockIdx.x * 64;
    const int grp = lane >> 4, sl = lane & 15;
    const int grpBase = lane & 48;

    const float4* tp4 = (const float4*)tp;
    const float4 b4 = *(const float4*)(bias + sl * 4);

    // ---- gather phase: 4 passes x (4 waves x 4 nodes) = 64 nodes ----
#pragma unroll
    for (int p = 0; p < 4; ++p) {
        const int nl = p * 16 + w * 4 + grp;  // node_local in [0,64)
        const int node = r0 + nl;

        const int start = offs[node];
        const int c = cnt[node];

        int cm = c;  // wave-uniform trip count
#pragma unroll
        for (int off = 32; off >= 1; off >>= 1) cm = max(cm, __shfl_xor(cm, off));

        float4 r = gcn_gather(tp4, eidx, node, start, c, cm, sl, grpBase);

        const float di = dinv[node];
        float* pl = &lhx[nl * 65 + sl * 4];
        pl[0] = fmaxf(fmaf(di, r.x, b4.x), 0.0f);
        pl[1] = fmaxf(fmaf(di, r.y, b4.y), 0.0f);
        pl[2] = fmaxf(fmaf(di, r.z, b4.z), 0.0f);
        pl[3] = fmaxf(fmaf(di, r.w, b4.w), 0.0f);
    }
    __syncthreads();

    // ---- gemm phase (K=64), input already in LDS ----
    const int c0 = __builtin_amdgcn_readfirstlane(w * 16);
    const float* Wp = W + c0;

    float acc[16];
#pragma unroll
    for (int cc = 0; cc < 16; ++cc) acc[cc] = 0.0f;

#pragma unroll
    for (int k = 0; k < HD; ++k) {
        float xk = lhx[lane * 65 + k];
#pragma unroll
        for (int cc = 0; cc < 16; ++cc)
            acc[cc] = fmaf(xk, Wp[k * HD + cc], acc[cc]);
    }

    float di2 = dinv[r0 + lane];  // source-side scale for NEXT aggregation
#pragma unroll
    for (int cc = 0; cc < 16; ++cc) acc[cc] *= di2;

    __syncthreads();  // reuse lhx as transpose buffer
#pragma unroll
    for (int cc = 0; cc < 16; ++cc) lhx[lane * 65 + c0 + cc] = acc[cc];
    __syncthreads();

#pragma unroll
    for (int i = 0; i < 16; ++i) {
        int r = i * 4 + w;
        tout[(size_t)(r0 + r) * HD + lane] = lhx[r * 65 + lane];
    }
}

// ---------------- gather: 4 nodes/wave, 16 lanes x float4 each --------------------
__global__ __launch_bounds__(256) void k_gather(const float* __restrict__ tp,
                                                const int* __restrict__ eidx,
                                                const int* __restrict__ offs,
                                                const int* __restrict__ cnt,
                                                const float* __restrict__ dinv,
                                                const float* __restrict__ bias,
                                                float* __restrict__ h) {
    const int wave = (blockIdx.x * 256 + threadIdx.x) >> 6;
    const int lane = threadIdx.x & 63;
    const int grp = lane >> 4, sl = lane & 15;
    const int grpBase = lane & 48;
    const int node = wave * 4 + grp;

    const float4* tp4 = (const float4*)tp;

    const int start = offs[node];
    const int c = cnt[node];

    // wave-uniform trip count = max degree in wave
    int cm = c;
#pragma unroll
    for (int off = 32; off >= 1; off >>= 1) cm = max(cm, __shfl_xor(cm, off));

    float4 a = gcn_gather(tp4, eidx, node, start, c, cm, sl, grpBase);

    const float di = dinv[node];
    const float4 b4 = *(const float4*)(bias + sl * 4);
    float4 r;
    r.x = fmaxf(fmaf(di, a.x, b4.x), 0.0f);
    r.y = fmaxf(fmaf(di, a.y, b4.y), 0.0f);
    r.z = fmaxf(fmaf(di, a.z, b4.z), 0.0f);
    r.w = fmaxf(fmaf(di, a.w, b4.w), 0.0f);
    ((float4*)h)[(size_t)node * 16 + sl] = r;
}

// ---------------- lead attention + pool + linear ----------------
__global__ __launch_bounds__(256) void k_attn(const float* __restrict__ h3,
                                              const float* __restrict__ Wa,
                                              const float* __restrict__ vvec,
                                              const float* __restrict__ Wl,
                                              const float* __restrict__ bl,
                                              float* __restrict__ out,
                                              float* __restrict__ lw) {
    __shared__ float lds_Wl[128 * 32];
    __shared__ float lds_h[4][LEADS * 64];
    __shared__ float lds_p[4][128];
    const int t = threadIdx.x;
    const int lane = t & 63;
    const int wid = t >> 6;

#pragma unroll
    for (int i = 0; i < 16; ++i) lds_Wl[t + i * 256] = Wl[t + i * 256];

    float wa[64];
#pragma unroll
    for (int k = 0; k < 64; ++k) wa[k] = Wa[k * 64 + lane];
    float vl = vvec[lane];
    __syncthreads();

    const int g = blockIdx.x * 4 + wid;

    float hv[LEADS];
#pragma unroll
    for (int r = 0; r < LEADS; ++r) {
        hv[r] = h3[(size_t)(g * LEADS + r) * 64 + lane];
        lds_h[wid][r * 64 + lane] = hv[r];
    }

    float s_[LEADS];
#pragma unroll
    for (int r = 0; r < LEADS; ++r) {
        float acc = 0.0f;
        const float4* h4 = (const float4*)&lds_h[wid][r * 64];
#pragma unroll
        for (int k4 = 0; k4 < 16; ++k4) {
            float4 hb = h4[k4];  // broadcast read
            acc = fmaf(hb.x, wa[4 * k4 + 0], acc);
            acc = fmaf(hb.y, wa[4 * k4 + 1], acc);
            acc = fmaf(hb.z, wa[4 * k4 + 2], acc);
            acc = fmaf(hb.w, wa[4 * k4 + 3], acc);
        }
        float sc = tanhf(acc) * vl;
#pragma unroll
        for (int off = 32; off >= 1; off >>= 1) sc += __shfl_xor(sc, off);
        s_[r] = sc;
    }

    float m = s_[0];
#pragma unroll
    for (int r = 1; r < LEADS; ++r) m = fmaxf(m, s_[r]);
    float wgt[LEADS];
    float sum = 0.0f;
#pragma unroll
    for (int r = 0; r < LEADS; ++r) {
        wgt[r] = expf(s_[r] - m);
        sum += wgt[r];
    }
    float inv = 1.0f / sum;

    float tmp = wgt[0] * inv;
#pragma unroll
    for (int r = 1; r < LEADS; ++r) tmp = (lane == r) ? wgt[r] * inv : tmp;
    if (lane < LEADS) lw[g * LEADS + lane] = tmp;

    float gmax = -1e30f, gsum = 0.0f;
#pragma unroll
    for (int r = 0; r < LEADS; ++r) {
        float wh = hv[r] * (wgt[r] * inv);
        gmax = fmaxf(gmax, wh);
        gsum += wh;
    }
    lds_p[wid][lane] = gmax;
    lds_p[wid][64 + lane] = gsum * (1.0f / 12.0f);

    int o = lane & 31, half = lane >> 5;
    float acc2 = 0.0f;
#pragma unroll
    for (int k = 0; k < 64; ++k) {
        int kk = half * 64 + k;
        acc2 = fmaf(lds_p[wid][kk], lds_Wl[kk * 32 + o], acc2);
    }
    acc2 += __shfl_xor(acc2, 32);
    if (lane < 32) out[g * 32 + lane] = fmaxf(acc2 + bl[lane], 0.0f);
}

// ---------------- launch ----------------
extern "C" void kernel_launch(void* const* d_in, const int* in_sizes, int n_in,
                              void* d_out, int out_size, void* d_ws, size_t ws_size,
                              hipStream_t stream) {
    const float* x  = (const float*)d_in[0];
    const int* ei   = (const int*)d_in[1];
    const int* src  = ei;
    const int* dst  = ei + N_EDGES;
    const float* W1 = (const float*)d_in[3];
    const float* b1 = (const float*)d_in[4];
    const float* W2 = (const float*)d_in[5];
    const float* b2 = (const float*)d_in[6];
    const float* W3 = (const float*)d_in[7];
    const float* b3 = (const float*)d_in[8];
    const float* Wa = (const float*)d_in[9];
    const float* vv = (const float*)d_in[10];
    const float* Wl = (const float*)d_in[11];
    const float* bl = (const float*)d_in[12];

    float* out = (float*)d_out;
    float* lw  = out + (size_t)NUM_GRAPHS * 32;

    float* dinv = (float*)d_ws;                       // N f32
    int* cnt    = (int*)(dinv + N_NODES);             // N
    int* offs   = cnt + N_NODES;                      // N
    int* bsum   = offs + N_NODES;                     // 1024
    int* eidx   = bsum + 1024;                        // E
    float* T    = (float*)(eidx + N_EDGES);           // N*64
    float* Hb   = T + (size_t)N_NODES * HD;           // N*64
    // rank aliases T: T is first written by k_gemm, strictly after k_fill
    // consumed rank (in-order stream).
    int* rank   = (int*)T;                            // E (aliased)

    const int gN = (N_NODES + 255) / 256;
    const int gE = (N_EDGES + 255) / 256;

    k_zero<<<gN, 256, 0, stream>>>(cnt);
    k_hist<<<gE, 256, 0, stream>>>(dst, cnt, rank);
    k_scan1<<<SCAN_BLOCKS, 256, 0, stream>>>(cnt, offs, bsum, dinv);
    k_scan2<<<1, 256, 0, stream>>>(bsum);
    k_scan3<<<gN, 256, 0, stream>>>(offs, bsum);
    k_fill<<<gE, 256, 0, stream>>>(src, dst, rank, offs, eidx);

    // layer 1 transform: T1 = dinv * (x @ W1)
    k_gemm<128><<<N_NODES / 64, 256, 0, stream>>>(x, W1, dinv, T);
    // fused: h1 = relu(agg(T1)+b1) in LDS; T2 = dinv * (h1 @ W2)
    k_fused<<<N_NODES / 64, 256, 0, stream>>>(T, eidx, offs, cnt, dinv, b1, W2, Hb);
    // fused: h2 = relu(agg(T2)+b2) in LDS; T3 = dinv * (h2 @ W3)
    k_fused<<<N_NODES / 64, 256, 0, stream>>>(Hb, eidx, offs, cnt, dinv, b2, W3, T);
    // layer 3 aggregation: h3 = relu(agg(T3)+b3)
    k_gather<<<N_NODES / 16, 256, 0, stream>>>(T, eidx, offs, cnt, dinv, b3, Hb);
    // attention + pool + linear
    k_attn<<<NUM_GRAPHS / 4, 256, 0, stream>>>(Hb, Wa, vv, Wl, bl, out, lw);
}

// Round 6
// 1251.953 us; speedup vs baseline: 1.2657x; 1.0267x over previous
//
#include <hip/hip_runtime.h>
#include <math.h>

#define N_NODES 600000
#define N_EDGES 2400000
#define HD 64
#define F_IN 128
#define LEADS 12
#define NUM_GRAPHS 50000
#define OUT_DIM 32
#define SCAN_BLOCKS 586  // ceil(600000/1024)

// native vector type for nontemporal builtins (HIP_vector_type is a class
// and is rejected by __builtin_nontemporal_*)
typedef float nf4 __attribute__((ext_vector_type(4)));

// ---------------- CSR build ----------------
__global__ __launch_bounds__(256) void k_zero(int* __restrict__ cnt) {
    int i = blockIdx.x * 256 + threadIdx.x;
    if (i < N_NODES) cnt[i] = 0;
}

// histogram AND per-edge rank (return value of the atomic). The atomic
// round-trip happens here once; k_fill no longer needs an atomic at all.
__global__ __launch_bounds__(256) void k_hist(const int* __restrict__ dst,
                                              int* __restrict__ cnt,
                                              int* __restrict__ rank) {
    int e = blockIdx.x * 256 + threadIdx.x;
    if (e < N_EDGES) rank[e] = atomicAdd(&cnt[dst[e]], 1);
}

__global__ __launch_bounds__(256) void k_scan1(const int* __restrict__ cnt,
                                               int* __restrict__ offs,
                                               int* __restrict__ bsum,
                                               float* __restrict__ dinv) {
    __shared__ int lds[256];
    int t = threadIdx.x;
    int base = blockIdx.x * 1024 + t * 4;
    int v[4];
#pragma unroll
    for (int j = 0; j < 4; ++j) v[j] = (base + j < N_NODES) ? cnt[base + j] : 0;
    // fused dinv: deg + self-loop
#pragma unroll
    for (int j = 0; j < 4; ++j)
        if (base + j < N_NODES) dinv[base + j] = rsqrtf((float)(v[j] + 1));
    int s = v[0] + v[1] + v[2] + v[3];
    lds[t] = s;
    __syncthreads();
    int val = s;
    for (int off = 1; off < 256; off <<= 1) {
        int other = (t >= off) ? lds[t - off] : 0;
        __syncthreads();
        val += other;
        lds[t] = val;
        __syncthreads();
    }
    if (t == 255) bsum[blockIdx.x] = val;
    int run = val - s;
#pragma unroll
    for (int j = 0; j < 4; ++j) {
        if (base + j < N_NODES) offs[base + j] = run;
        run += v[j];
    }
}

__global__ __launch_bounds__(256) void k_scan2(int* __restrict__ bsum) {
    __shared__ int lds[SCAN_BLOCKS];
    for (int i = threadIdx.x; i < SCAN_BLOCKS; i += 256) lds[i] = bsum[i];
    __syncthreads();
    if (threadIdx.x == 0) {
        int run = 0;
        for (int i = 0; i < SCAN_BLOCKS; ++i) {
            int c = lds[i];
            lds[i] = run;
            run += c;
        }
    }
    __syncthreads();
    for (int i = threadIdx.x; i < SCAN_BLOCKS; i += 256) bsum[i] = lds[i];
}

__global__ __launch_bounds__(256) void k_scan3(int* __restrict__ offs,
                                               const int* __restrict__ bsum) {
    int i = blockIdx.x * 256 + threadIdx.x;
    if (i < N_NODES) offs[i] += bsum[i >> 10];
}

// atomic-free fill: position = segment base + precomputed rank.
__global__ __launch_bounds__(256) void k_fill(const int* __restrict__ src,
                                              const int* __restrict__ dst,
                                              const int* __restrict__ rank,
                                              const int* __restrict__ offs,
                                              int* __restrict__ eidx) {
    int e = blockIdx.x * 256 + threadIdx.x;
    if (e < N_EDGES) {
        int p = offs[dst[e]] + rank[e];
        eidx[p] = src[e];
    }
}

// ---------------- latency-optimized per-node edge gather ----------------
// 16-lane group accumulates 64 feature floats (float4/lane) over the node's
// edge list. Edge indices are prefetched coalesced (lane sl loads
// eidx[start+sl]) and distributed via shfl; 8 row-loads kept in flight,
// branch-free: masked slots load the node's OWN row (L1-hot) and are
// nulled via fmaf(mask, ...). cm must be the wave-uniform max degree.
__device__ __forceinline__ float4 gcn_gather(const float4* __restrict__ tp4,
                                             const int* __restrict__ eidx,
                                             int node, int start, int c, int cm,
                                             int sl, int grpBase) {
    float4 a0 = tp4[(size_t)node * 16 + sl];  // self-loop
    float4 a1 = {0.0f, 0.0f, 0.0f, 0.0f};
    float4 a2 = {0.0f, 0.0f, 0.0f, 0.0f};
    float4 a3 = {0.0f, 0.0f, 0.0f, 0.0f};

    for (int base = 0; base < cm; base += 16) {
        // batch of up to 16 edge indices, one coalesced load per group;
        // masked lanes hold `node` so shfl past `c` is safe
        int idxreg = (base + sl < c) ? eidx[start + base + sl] : node;
        int take = cm - base;
        if (take > 16) take = 16;
        for (int j = 0; j < take; j += 8) {
            int i0 = __shfl(idxreg, grpBase + j + 0);
            int i1 = __shfl(idxreg, grpBase + j + 1);
            int i2 = __shfl(idxreg, grpBase + j + 2);
            int i3 = __shfl(idxreg, grpBase + j + 3);
            int i4 = __shfl(idxreg, grpBase + j + 4);
            int i5 = __shfl(idxreg, grpBase + j + 5);
            int i6 = __shfl(idxreg, grpBase + j + 6);
            int i7 = __shfl(idxreg, grpBase + j + 7);
            float m0 = (base + j + 0 < c) ? 1.0f : 0.0f;
            float m1 = (base + j + 1 < c) ? 1.0f : 0.0f;
            float m2 = (base + j + 2 < c) ? 1.0f : 0.0f;
            float m3 = (base + j + 3 < c) ? 1.0f : 0.0f;
            float m4 = (base + j + 4 < c) ? 1.0f : 0.0f;
            float m5 = (base + j + 5 < c) ? 1.0f : 0.0f;
            float m6 = (base + j + 6 < c) ? 1.0f : 0.0f;
            float m7 = (base + j + 7 < c) ? 1.0f : 0.0f;
            // 8 independent loads in flight (masked slots fall back to
            // `node` -> L1 hit, no extra HBM traffic)
            float4 v0 = tp4[(size_t)i0 * 16 + sl];
            float4 v1 = tp4[(size_t)i1 * 16 + sl];
            float4 v2 = tp4[(size_t)i2 * 16 + sl];
            float4 v3 = tp4[(size_t)i3 * 16 + sl];
            float4 v4 = tp4[(size_t)i4 * 16 + sl];
            float4 v5 = tp4[(size_t)i5 * 16 + sl];
            float4 v6 = tp4[(size_t)i6 * 16 + sl];
            float4 v7 = tp4[(size_t)i7 * 16 + sl];
            a0.x = fmaf(m0, v0.x, a0.x); a0.y = fmaf(m0, v0.y, a0.y);
            a0.z = fmaf(m0, v0.z, a0.z); a0.w = fmaf(m0, v0.w, a0.w);
            a1.x = fmaf(m1, v1.x, a1.x); a1.y = fmaf(m1, v1.y, a1.y);
            a1.z = fmaf(m1, v1.z, a1.z); a1.w = fmaf(m1, v1.w, a1.w);
            a2.x = fmaf(m2, v2.x, a2.x); a2.y = fmaf(m2, v2.y, a2.y);
            a2.z = fmaf(m2, v2.z, a2.z); a2.w = fmaf(m2, v2.w, a2.w);
            a3.x = fmaf(m3, v3.x, a3.x); a3.y = fmaf(m3, v3.y, a3.y);
            a3.z = fmaf(m3, v3.z, a3.z); a3.w = fmaf(m3, v3.w, a3.w);
            a0.x = fmaf(m4, v4.x, a0.x); a0.y = fmaf(m4, v4.y, a0.y);
            a0.z = fmaf(m4, v4.z, a0.z); a0.w = fmaf(m4, v4.w, a0.w);
            a1.x = fmaf(m5, v5.x, a1.x); a1.y = fmaf(m5, v5.y, a1.y);
            a1.z = fmaf(m5, v5.z, a1.z); a1.w = fmaf(m5, v5.w, a1.w);
            a2.x = fmaf(m6, v6.x, a2.x); a2.y = fmaf(m6, v6.y, a2.y);
            a2.z = fmaf(m6, v6.z, a2.z); a2.w = fmaf(m6, v6.w, a2.w);
            a3.x = fmaf(m7, v7.x, a3.x); a3.y = fmaf(m7, v7.y, a3.y);
            a3.z = fmaf(m7, v7.z, a3.z); a3.w = fmaf(m7, v7.w, a3.w);
        }
    }
    a0.x += a1.x + a2.x + a3.x;
    a0.y += a1.y + a2.y + a3.y;
    a0.z += a1.z + a2.z + a3.z;
    a0.w += a1.w + a2.w + a3.w;
    return a0;
}

// ---------------- GEMM: lane=row, scalar W, 16 cols per wave --------------------
// t'[r][c] = dinv[r] * sum_k in[r][k] * W[k][c].  64 rows per block, wave w -> cols [16w,16w+16)
// NT-loads the streamed input (never reused) so the T output stays
// L3-resident for the next kernel's random gather; T stores stay NORMAL
// (write-allocate = prefetch into L3).
template <int K>
__global__ __launch_bounds__(256) void k_gemm(const float* __restrict__ in,
                                              const float* __restrict__ W,
                                              const float* __restrict__ dinv,
                                              float* __restrict__ tout) {
    __shared__ float lx[64 * (K + 1)];
    const int t = threadIdx.x;
    const int lane = t & 63;
    const int r0 = blockIdx.x * 64;

    // stage 64 rows, coalesced float4, scalar writes into padded LDS (stride K+1)
#pragma unroll
    for (int i = 0; i < K / 16; ++i) {
        int f = (t + i * 256) * 4;
        int r = f / K, k = f % K;
        nf4 v = __builtin_nontemporal_load(
            (const nf4*)(in + (size_t)(r0 + r) * K + k));
        float* p = &lx[r * (K + 1) + k];
        p[0] = v.x; p[1] = v.y; p[2] = v.z; p[3] = v.w;
    }
    __syncthreads();

    // wave-uniform column base so W loads become s_load
    const int c0 = __builtin_amdgcn_readfirstlane((t >> 6) * 16);
    const float* Wp = W + c0;

    float acc[16];
#pragma unroll
    for (int cc = 0; cc < 16; ++cc) acc[cc] = 0.0f;

#pragma unroll
    for (int k = 0; k < K; ++k) {
        float xk = lx[lane * (K + 1) + k];  // stride K+1 -> conflict-free
#pragma unroll
        for (int cc = 0; cc < 16; ++cc)
            acc[cc] = fmaf(xk, Wp[k * HD + cc], acc[cc]);  // SGPR operand
    }

    float di = dinv[r0 + lane];
#pragma unroll
    for (int cc = 0; cc < 16; ++cc) acc[cc] *= di;

    __syncthreads();  // reuse lx as transpose buffer (stride 65)
#pragma unroll
    for (int cc = 0; cc < 16; ++cc) lx[lane * 65 + c0 + cc] = acc[cc];
    __syncthreads();

    const int w = t >> 6;
#pragma unroll
    for (int i = 0; i < 16; ++i) {
        int r = i * 4 + w;
        tout[(size_t)(r0 + r) * HD + lane] = lx[r * 65 + lane];  // normal: allocate
    }
}

// ---------------- fused gather(layer i) + gemm(layer i+1) ----------------
// Per block: 64 nodes. Gather phase writes relu(di*agg + b) straight into the
// padded LDS tile (stride 65); gemm phase consumes it without the global
// Hb round-trip. tout is NT-stored: it is dead until the NEXT kernel, and
// bypassing allocation protects the random-read working set (tp) in L3.
__global__ __launch_bounds__(256) void k_fused(const float* __restrict__ tp,
                                               const int* __restrict__ eidx,
                                               const int* __restrict__ offs,
                                               const int* __restrict__ cnt,
                                               const float* __restrict__ dinv,
                                               const float* __restrict__ bias,
                                               const float* __restrict__ W,
                                               float* __restrict__ tout) {
    __shared__ float lhx[64 * 65];
    const int t = threadIdx.x;
    const int lane = t & 63;
    const int w = t >> 6;
    const int r0 = blockIdx.x * 64;
    const int grp = lane >> 4, sl = lane & 15;
    const int grpBase = lane & 48;

    const float4* tp4 = (const float4*)tp;
    const float4 b4 = *(const float4*)(bias + sl * 4);

    // ---- gather phase: 4 passes x (4 waves x 4 nodes) = 64 nodes ----
#pragma unroll
    for (int p = 0; p < 4; ++p) {
        const int nl = p * 16 + w * 4 + grp;  // node_local in [0,64)
        const int node = r0 + nl;

        const int start = offs[node];
        const int c = cnt[node];

        int cm = c;  // wave-uniform trip count
#pragma unroll
        for (int off = 32; off >= 1; off >>= 1) cm = max(cm, __shfl_xor(cm, off));

        float4 r = gcn_gather(tp4, eidx, node, start, c, cm, sl, grpBase);

        const float di = dinv[node];
        float* pl = &lhx[nl * 65 + sl * 4];
        pl[0] = fmaxf(fmaf(di, r.x, b4.x), 0.0f);
        pl[1] = fmaxf(fmaf(di, r.y, b4.y), 0.0f);
        pl[2] = fmaxf(fmaf(di, r.z, b4.z), 0.0f);
        pl[3] = fmaxf(fmaf(di, r.w, b4.w), 0.0f);
    }
    __syncthreads();

    // ---- gemm phase (K=64), input already in LDS ----
    const int c0 = __builtin_amdgcn_readfirstlane(w * 16);
    const float* Wp = W + c0;

    float acc[16];
#pragma unroll
    for (int cc = 0; cc < 16; ++cc) acc[cc] = 0.0f;

#pragma unroll
    for (int k = 0; k < HD; ++k) {
        float xk = lhx[lane * 65 + k];
#pragma unroll
        for (int cc = 0; cc < 16; ++cc)
            acc[cc] = fmaf(xk, Wp[k * HD + cc], acc[cc]);
    }

    float di2 = dinv[r0 + lane];  // source-side scale for NEXT aggregation
#pragma unroll
    for (int cc = 0; cc < 16; ++cc) acc[cc] *= di2;

    __syncthreads();  // reuse lhx as transpose buffer
#pragma unroll
    for (int cc = 0; cc < 16; ++cc) lhx[lane * 65 + c0 + cc] = acc[cc];
    __syncthreads();

#pragma unroll
    for (int i = 0; i < 16; ++i) {
        int r = i * 4 + w;
        __builtin_nontemporal_store(lhx[r * 65 + lane],
                                    &tout[(size_t)(r0 + r) * HD + lane]);
    }
}

// ---------------- gather: 4 nodes/wave, 16 lanes x float4 each --------------------
__global__ __launch_bounds__(256) void k_gather(const float* __restrict__ tp,
                                                const int* __restrict__ eidx,
                                                const int* __restrict__ offs,
                                                const int* __restrict__ cnt,
                                                const float* __restrict__ dinv,
                                                const float* __restrict__ bias,
                                                float* __restrict__ h) {
    const int wave = (blockIdx.x * 256 + threadIdx.x) >> 6;
    const int lane = threadIdx.x & 63;
    const int grp = lane >> 4, sl = lane & 15;
    const int grpBase = lane & 48;
    const int node = wave * 4 + grp;

    const float4* tp4 = (const float4*)tp;

    const int start = offs[node];
    const int c = cnt[node];

    // wave-uniform trip count = max degree in wave
    int cm = c;
#pragma unroll
    for (int off = 32; off >= 1; off >>= 1) cm = max(cm, __shfl_xor(cm, off));

    float4 a = gcn_gather(tp4, eidx, node, start, c, cm, sl, grpBase);

    const float di = dinv[node];
    const float4 b4 = *(const float4*)(bias + sl * 4);
    nf4 r;
    r.x = fmaxf(fmaf(di, a.x, b4.x), 0.0f);
    r.y = fmaxf(fmaf(di, a.y, b4.y), 0.0f);
    r.z = fmaxf(fmaf(di, a.z, b4.z), 0.0f);
    r.w = fmaxf(fmaf(di, a.w, b4.w), 0.0f);
    __builtin_nontemporal_store(r, &((nf4*)h)[(size_t)node * 16 + sl]);
}

// ---------------- lead attention + pool + linear ----------------
__global__ __launch_bounds__(256) void k_attn(const float* __restrict__ h3,
                                              const float* __restrict__ Wa,
                                              const float* __restrict__ vvec,
                                              const float* __restrict__ Wl,
                                              const float* __restrict__ bl,
                                              float* __restrict__ out,
                                              float* __restrict__ lw) {
    __shared__ float lds_Wl[128 * 32];
    __shared__ float lds_h[4][LEADS * 64];
    __shared__ float lds_p[4][128];
    const int t = threadIdx.x;
    const int lane = t & 63;
    const int wid = t >> 6;

#pragma unroll
    for (int i = 0; i < 16; ++i) lds_Wl[t + i * 256] = Wl[t + i * 256];

    float wa[64];
#pragma unroll
    for (int k = 0; k < 64; ++k) wa[k] = Wa[k * 64 + lane];
    float vl = vvec[lane];
    __syncthreads();

    const int g = blockIdx.x * 4 + wid;

    float hv[LEADS];
#pragma unroll
    for (int r = 0; r < LEADS; ++r) {
        hv[r] = h3[(size_t)(g * LEADS + r) * 64 + lane];
        lds_h[wid][r * 64 + lane] = hv[r];
    }

    float s_[LEADS];
#pragma unroll
    for (int r = 0; r < LEADS; ++r) {
        float acc = 0.0f;
        const float4* h4 = (const float4*)&lds_h[wid][r * 64];
#pragma unroll
        for (int k4 = 0; k4 < 16; ++k4) {
            float4 hb = h4[k4];  // broadcast read
            acc = fmaf(hb.x, wa[4 * k4 + 0], acc);
            acc = fmaf(hb.y, wa[4 * k4 + 1], acc);
            acc = fmaf(hb.z, wa[4 * k4 + 2], acc);
            acc = fmaf(hb.w, wa[4 * k4 + 3], acc);
        }
        float sc = tanhf(acc) * vl;
#pragma unroll
        for (int off = 32; off >= 1; off >>= 1) sc += __shfl_xor(sc, off);
        s_[r] = sc;
    }

    float m = s_[0];
#pragma unroll
    for (int r = 1; r < LEADS; ++r) m = fmaxf(m, s_[r]);
    float wgt[LEADS];
    float sum = 0.0f;
#pragma unroll
    for (int r = 0; r < LEADS; ++r) {
        wgt[r] = expf(s_[r] - m);
        sum += wgt[r];
    }
    float inv = 1.0f / sum;

    float tmp = wgt[0] * inv;
#pragma unroll
    for (int r = 1; r < LEADS; ++r) tmp = (lane == r) ? wgt[r] * inv : tmp;
    if (lane < LEADS) lw[g * LEADS + lane] = tmp;

    float gmax = -1e30f, gsum = 0.0f;
#pragma unroll
    for (int r = 0; r < LEADS; ++r) {
        float wh = hv[r] * (wgt[r] * inv);
        gmax = fmaxf(gmax, wh);
        gsum += wh;
    }
    lds_p[wid][lane] = gmax;
    lds_p[wid][64 + lane] = gsum * (1.0f / 12.0f);

    int o = lane & 31, half = lane >> 5;
    float acc2 = 0.0f;
#pragma unroll
    for (int k = 0; k < 64; ++k) {
        int kk = half * 64 + k;
        acc2 = fmaf(lds_p[wid][kk], lds_Wl[kk * 32 + o], acc2);
    }
    acc2 += __shfl_xor(acc2, 32);
    if (lane < 32) out[g * 32 + lane] = fmaxf(acc2 + bl[lane], 0.0f);
}

// ---------------- launch ----------------
extern "C" void kernel_launch(void* const* d_in, const int* in_sizes, int n_in,
                              void* d_out, int out_size, void* d_ws, size_t ws_size,
                              hipStream_t stream) {
    const float* x  = (const float*)d_in[0];
    const int* ei   = (const int*)d_in[1];
    const int* src  = ei;
    const int* dst  = ei + N_EDGES;
    const float* W1 = (const float*)d_in[3];
    const float* b1 = (const float*)d_in[4];
    const float* W2 = (const float*)d_in[5];
    const float* b2 = (const float*)d_in[6];
    const float* W3 = (const float*)d_in[7];
    const float* b3 = (const float*)d_in[8];
    const float* Wa = (const float*)d_in[9];
    const float* vv = (const float*)d_in[10];
    const float* Wl = (const float*)d_in[11];
    const float* bl = (const float*)d_in[12];

    float* out = (float*)d_out;
    float* lw  = out + (size_t)NUM_GRAPHS * 32;

    float* dinv = (float*)d_ws;                       // N f32
    int* cnt    = (int*)(dinv + N_NODES);             // N
    int* offs   = cnt + N_NODES;                      // N
    int* bsum   = offs + N_NODES;                     // 1024
    int* eidx   = bsum + 1024;                        // E
    float* T    = (float*)(eidx + N_EDGES);           // N*64
    float* Hb   = T + (size_t)N_NODES * HD;           // N*64
    // rank aliases T: T is first written by k_gemm, strictly after k_fill
    // consumed rank (in-order stream).
    int* rank   = (int*)T;                            // E (aliased)

    const int gN = (N_NODES + 255) / 256;
    const int gE = (N_EDGES + 255) / 256;

    k_zero<<<gN, 256, 0, stream>>>(cnt);
    k_hist<<<gE, 256, 0, stream>>>(dst, cnt, rank);
    k_scan1<<<SCAN_BLOCKS, 256, 0, stream>>>(cnt, offs, bsum, dinv);
    k_scan2<<<1, 256, 0, stream>>>(bsum);
    k_scan3<<<gN, 256, 0, stream>>>(offs, bsum);
    k_fill<<<gE, 256, 0, stream>>>(src, dst, rank, offs, eidx);

    // layer 1 transform: T1 = dinv * (x @ W1)  (x NT-loaded, T1 allocates in L3)
    k_gemm<128><<<N_NODES / 64, 256, 0, stream>>>(x, W1, dinv, T);
    // fused: h1 = relu(agg(T1)+b1) in LDS; T2 = dinv * (h1 @ W2)  (T2 NT-stored)
    k_fused<<<N_NODES / 64, 256, 0, stream>>>(T, eidx, offs, cnt, dinv, b1, W2, Hb);
    // fused: h2 = relu(agg(T2)+b2) in LDS; T3 = dinv * (h2 @ W3)  (T3 NT-stored)
    k_fused<<<N_NODES / 64, 256, 0, stream>>>(Hb, eidx, offs, cnt, dinv, b2, W3, T);
    // layer 3 aggregation: h3 = relu(agg(T3)+b3)  (h3 NT-stored)
    k_gather<<<N_NODES / 16, 256, 0, stream>>>(T, eidx, offs, cnt, dinv, b3, Hb);
    // attention + pool + linear
    k_attn<<<NUM_GRAPHS / 4, 256, 0, stream>>>(Hb, Wa, vv, Wl, bl, out, lw);
}